// Round 8
// baseline (416.800 us; speedup 1.0000x reference)
//
#include <hip/hip_runtime.h>
#include <hip/hip_bf16.h>

// V=50000, E=1600000, D=64, EF=16, node_in=74, NV=64 (derived at launch).
// Flat-tile design, R8:
//   CSR (dst-grouped, monotone off via 3-kernel scan) built once.
//   eas_win: XCD-windowed scatter writes srcs[pos] + bf16 eas[pos] (sorted
//     edge payload) -> edge kernel streams them SEQUENTIALLY.
//   edge_tile: ptile[t] = colsum over tile rows of relu([h[src],ea,1]@W1')
//     (W1' row 80 = b1 flag-bias; masked rows contribute 0). 3-deep pipeline;
//     only the h[src] gather is random (6.4 MB working set).
//   ln_node:  S[u] = sum of ptile rows [firstTile[u], firstTile[u]+ceil(deg/16));
//             h' = LN(h + (S@W2)/deg + b2 [deg>0]).

typedef __attribute__((ext_vector_type(8))) short short8b;   // 8 bf16
typedef __attribute__((ext_vector_type(4))) float f32x4;     // MFMA C/D
typedef __attribute__((ext_vector_type(4))) unsigned int u32x4;

static __device__ __forceinline__ short f2bf(float f) {
  union { __hip_bfloat16 h; short s; } u; u.h = __float2bfloat16(f); return u.s;
}
static __device__ __forceinline__ float bf2f(short s) {
  union { unsigned u; float f; } v; v.u = ((unsigned)(unsigned short)s) << 16; return v.f;
}
static __device__ __forceinline__ short8b zero8() {
  short8b z;
#pragma unroll
  for (int i = 0; i < 8; ++i) z[i] = 0;
  return z;
}
static __device__ __forceinline__ short8b and8(short8b a, unsigned m) {
  u32x4 x = __builtin_bit_cast(u32x4, a);
#pragma unroll
  for (int i = 0; i < 4; ++i) x[i] &= m;
  return __builtin_bit_cast(short8b, x);
}

// ----------------------------------------------------------------- degree
__global__ void deg_kernel(const int* __restrict__ ei, int* __restrict__ deg, int E_) {
  int i = blockIdx.x * blockDim.x + threadIdx.x;
  if (i < E_) atomicAdd(&deg[ei[E_ + i]], 1);
}

// ------------------------------------- monotone exclusive scan (3 kernels)
__global__ void scanA_kernel(const int* __restrict__ deg, int* __restrict__ partD,
                             int* __restrict__ partT, int V_) {
  __shared__ int sd[256], st[256];
  int t = threadIdx.x;
  int v = blockIdx.x * 256 + t;
  int d = (v < V_) ? deg[v] : 0;
  sd[t] = d; st[t] = (d + 15) >> 4;
  __syncthreads();
  for (int o = 128; o; o >>= 1) {
    if (t < o) { sd[t] += sd[t + o]; st[t] += st[t + o]; }
    __syncthreads();
  }
  if (t == 0) { partD[blockIdx.x] = sd[0]; partT[blockIdx.x] = st[0]; }
}

__global__ void scanB_kernel(int* __restrict__ partD, int* __restrict__ partT,
                             int* __restrict__ gtot, int nb) {
  __shared__ int sd[256], st[256];
  int t = threadIdx.x;  // 256 >= nb
  int d = (t < nb) ? partD[t] : 0;
  int tt = (t < nb) ? partT[t] : 0;
  sd[t] = d; st[t] = tt;
  __syncthreads();
  for (int o = 1; o < 256; o <<= 1) {
    int ad = (t >= o) ? sd[t - o] : 0;
    int at = (t >= o) ? st[t - o] : 0;
    __syncthreads();
    sd[t] += ad; st[t] += at;
    __syncthreads();
  }
  if (t < nb) { partD[t] = t ? sd[t - 1] : 0; partT[t] = t ? st[t - 1] : 0; }
  if (t == nb - 1) { gtot[0] = sd[t]; gtot[1] = st[t]; }
}

__global__ void scanC_kernel(const int* __restrict__ deg, const int* __restrict__ partD,
                             const int* __restrict__ partT, int* __restrict__ off,
                             int* __restrict__ cursor, int* __restrict__ firstT, int V_) {
  __shared__ int sd[256], st[256];
  int t = threadIdx.x;
  int v = blockIdx.x * 256 + t;
  int d = (v < V_) ? deg[v] : 0;
  int td = (d + 15) >> 4;
  sd[t] = d; st[t] = td;
  __syncthreads();
  for (int o = 1; o < 256; o <<= 1) {
    int ad = (t >= o) ? sd[t - o] : 0;
    int at = (t >= o) ? st[t - o] : 0;
    __syncthreads();
    sd[t] += ad; st[t] += at;
    __syncthreads();
  }
  if (v < V_) {
    int eoff = partD[blockIdx.x] + sd[t] - d;
    int toff = partT[blockIdx.x] + st[t] - td;
    off[v] = eoff; cursor[v] = eoff; firstT[v] = toff;
  }
}

__global__ void tile_fill_kernel(const int* __restrict__ deg, const int* __restrict__ off,
                                 const int* __restrict__ firstTile, int2* __restrict__ tinfo,
                                 int V_) {
  int v = blockIdx.x * blockDim.x + threadIdx.x;
  if (v >= V_) return;
  int d = deg[v], o = off[v], T0 = firstTile[v];
  int nt = (d + 15) >> 4;
  for (int j = 0; j < nt; ++j)
    tinfo[T0 + j] = make_int2(o + 16 * j, min(16, d - 16 * j));
}

// ----------------- srcs + sorted-eas scatter, XCD-windowed (L2-resident)
__global__ void eas_win_kernel(const int* __restrict__ ei, const float* __restrict__ ea,
                               int* __restrict__ cursor, int* __restrict__ srcs,
                               short* __restrict__ eas, int E_, int Vw) {
  const int wb  = blockIdx.x & 7;          // XCD id (round-robin mapping)
  const int sub = blockIdx.x >> 3;
  const int nsub = gridDim.x >> 3;
  const int lo = wb * Vw, hi = lo + Vw;
  for (int i = sub * blockDim.x + threadIdx.x; i < E_; i += nsub * blockDim.x) {
    int dst = ei[E_ + i];
    if (dst >= lo && dst < hi) {
      int pos = atomicAdd(&cursor[dst], 1);
      srcs[pos] = ei[i];
      const float4* row = reinterpret_cast<const float4*>(ea + (size_t)i * 16);
      float4 q0 = row[0], q1 = row[1], q2 = row[2], q3 = row[3];
      short8b s0, s1;
      s0[0]=f2bf(q0.x); s0[1]=f2bf(q0.y); s0[2]=f2bf(q0.z); s0[3]=f2bf(q0.w);
      s0[4]=f2bf(q1.x); s0[5]=f2bf(q1.y); s0[6]=f2bf(q1.z); s0[7]=f2bf(q1.w);
      s1[0]=f2bf(q2.x); s1[1]=f2bf(q2.y); s1[2]=f2bf(q2.z); s1[3]=f2bf(q2.w);
      s1[4]=f2bf(q3.x); s1[5]=f2bf(q3.y); s1[6]=f2bf(q3.z); s1[7]=f2bf(q3.w);
      short8b* outp = reinterpret_cast<short8b*>(eas + (size_t)pos * 16);
      outp[0] = s0; outp[1] = s1;
    }
  }
}

// ------------------------------------------------------- embed (MFMA tiles)
__global__ __launch_bounds__(256) void embed_mfma(
    const float* __restrict__ Z, const float* __restrict__ vm,
    const float* __restrict__ nW, const float* __restrict__ nb,
    float* __restrict__ h, short* __restrict__ hbf, int V_) {
  const int lane = threadIdx.x & 63;
  const int r = lane & 15, g = lane >> 4;
  short8b wf[4][3];
#pragma unroll
  for (int n = 0; n < 4; ++n)
#pragma unroll
    for (int s = 0; s < 3; ++s)
#pragma unroll
      for (int i = 0; i < 8; ++i) {
        int k = s * 32 + 8 * g + i;
        wf[n][s][i] = f2bf(k < 74 ? nW[k * 64 + n * 16 + r] : 0.0f);
      }
  float nb4[4];
#pragma unroll
  for (int n = 0; n < 4; ++n) nb4[n] = nb[n * 16 + r];

  const int ntiles = (V_ + 15) >> 4;
  const int nw = (gridDim.x * blockDim.x) >> 6;
  const int w0 = (blockIdx.x * blockDim.x + threadIdx.x) >> 6;
  for (int tile = w0; tile < ntiles; tile += nw) {
    const int v0 = tile << 4;
    const int vr = min(v0 + r, V_ - 1);
    const float4* z4 = reinterpret_cast<const float4*>(Z + (size_t)vr * 64);
    float4 p0 = z4[2 * g], p1 = z4[2 * g + 1];
    float4 p2 = z4[8 + 2 * g], p3 = z4[9 + 2 * g];
    short8b a0, a1, a2 = zero8();
    a0[0]=f2bf(p0.x); a0[1]=f2bf(p0.y); a0[2]=f2bf(p0.z); a0[3]=f2bf(p0.w);
    a0[4]=f2bf(p1.x); a0[5]=f2bf(p1.y); a0[6]=f2bf(p1.z); a0[7]=f2bf(p1.w);
    a1[0]=f2bf(p2.x); a1[1]=f2bf(p2.y); a1[2]=f2bf(p2.z); a1[3]=f2bf(p2.w);
    a1[4]=f2bf(p3.x); a1[5]=f2bf(p3.y); a1[6]=f2bf(p3.z); a1[7]=f2bf(p3.w);
    const float* vrow = vm + (size_t)vr * 10;
    if (g == 0) {
#pragma unroll
      for (int i = 0; i < 8; ++i) a2[i] = f2bf(vrow[i]);
    } else if (g == 1) {
      a2[0] = f2bf(vrow[8]); a2[1] = f2bf(vrow[9]);
    }
    f32x4 acc[4];
#pragma unroll
    for (int n = 0; n < 4; ++n) {
      acc[n] = f32x4{nb4[n], nb4[n], nb4[n], nb4[n]};
      acc[n] = __builtin_amdgcn_mfma_f32_16x16x32_bf16(a0, wf[n][0], acc[n], 0, 0, 0);
      acc[n] = __builtin_amdgcn_mfma_f32_16x16x32_bf16(a1, wf[n][1], acc[n], 0, 0, 0);
      acc[n] = __builtin_amdgcn_mfma_f32_16x16x32_bf16(a2, wf[n][2], acc[n], 0, 0, 0);
    }
#pragma unroll
    for (int i = 0; i < 4; ++i) {
      int u = v0 + 4 * g + i;
      if (u < V_) {
#pragma unroll
        for (int n = 0; n < 4; ++n) {
          h[(size_t)u * 64 + n * 16 + r] = acc[n][i];
          hbf[(size_t)u * 64 + n * 16 + r] = f2bf(acc[n][i]);
        }
      }
    }
  }
}

// ---------------------------------------------------- edge tile kernel v2
// Sequential srcs/eas streams; only h[src] gather is random.
// Pipeline: srcs 2-ahead -> h 1-ahead; eas 1-ahead (independent); tinfo 3-ahead.
__global__ __launch_bounds__(256) void edge_tile_kernel(
    const short* __restrict__ hbf, const int* __restrict__ srcs,
    const short* __restrict__ eas, const int2* __restrict__ tinfo,
    const int* __restrict__ gtot,
    const float* __restrict__ W1, const float* __restrict__ b1,
    short* __restrict__ ptile, int E_) {
  const int lane = threadIdx.x & 63;
  const int r = lane & 15, g = lane >> 4;
  // W1' fragments: rows 0..79 = W1, row 80 = b1, rows 81..95 = 0
  short8b w1f[4][3];
#pragma unroll
  for (int n = 0; n < 4; ++n)
#pragma unroll
    for (int s = 0; s < 3; ++s)
#pragma unroll
      for (int i = 0; i < 8; ++i) {
        int k = s * 32 + 8 * g + i;
        float wv = (k < 80) ? W1[k * 64 + n * 16 + r]
                 : (k == 80 ? b1[n * 16 + r] : 0.0f);
        w1f[n][s][i] = f2bf(wv);
      }
  const int ntiles = gtot[1];
  const int nw = (gridDim.x * blockDim.x) >> 6;
  int t = (blockIdx.x * blockDim.x + threadIdx.x) >> 6;
  if (t >= ntiles) return;
  auto info = [&](int tt) { return tinfo[min(tt, ntiles - 1)]; };

  // prologue: tile t fully loaded, srcs of t+1 in flight
  int2 tc  = tinfo[t];
  int2 ti1 = info(t + nw);
  int2 ti2 = info(t + 2 * nw);
  int s0 = srcs[tc.x + r];                       // arrays padded +16: no clamp
  short8b e0v = zero8();
  if (g < 2) e0v = *reinterpret_cast<const short8b*>(eas + ((size_t)(tc.x + r)) * 16 + 8 * g);
  const short* hrow0 = hbf + (size_t)s0 * 64;
  short8b a0 = *reinterpret_cast<const short8b*>(hrow0 + 8 * g);
  short8b a1 = *reinterpret_cast<const short8b*>(hrow0 + 32 + 8 * g);
  int s1 = srcs[ti1.x + r];

  while (true) {
    // issue loads for tile t+1 (h from s1; eas sequential)
    const short* hrow1 = hbf + (size_t)s1 * 64;
    short8b a0n = *reinterpret_cast<const short8b*>(hrow1 + 8 * g);
    short8b a1n = *reinterpret_cast<const short8b*>(hrow1 + 32 + 8 * g);
    short8b e1v = zero8();
    if (g < 2) e1v = *reinterpret_cast<const short8b*>(eas + ((size_t)(ti1.x + r)) * 16 + 8 * g);
    // srcs for t+2, tinfo for t+3
    int s2 = srcs[ti2.x + r];
    int2 ti3 = info(t + 3 * nw);
    // tail masking (rows >= nrows contribute 0 via flag-bias trick)
    unsigned m = (r < tc.y) ? 0xFFFFFFFFu : 0u;
    short8b b0 = and8(a0, m);
    short8b b1v_ = and8(a1, m);
    short8b b2_ = zero8();
    if (g < 2) b2_ = and8(e0v, m);
    if (g == 2) b2_[0] = (short)(m & 0x3F80u);  // flag feature = 1.0bf16
    // GEMM1: 16x96 @ 96x64
    f32x4 acc[4];
#pragma unroll
    for (int n = 0; n < 4; ++n) {
      acc[n] = f32x4{0.f, 0.f, 0.f, 0.f};
      acc[n] = __builtin_amdgcn_mfma_f32_16x16x32_bf16(b0, w1f[n][0], acc[n], 0, 0, 0);
      acc[n] = __builtin_amdgcn_mfma_f32_16x16x32_bf16(b1v_, w1f[n][1], acc[n], 0, 0, 0);
      acc[n] = __builtin_amdgcn_mfma_f32_16x16x32_bf16(b2_, w1f[n][2], acc[n], 0, 0, 0);
    }
    // relu + sum over 16 rows
    float s4[4];
#pragma unroll
    for (int n = 0; n < 4; ++n) {
      float s = (fmaxf(acc[n][0], 0.f) + fmaxf(acc[n][1], 0.f))
              + (fmaxf(acc[n][2], 0.f) + fmaxf(acc[n][3], 0.f));
      s += __shfl_xor(s, 16);
      s += __shfl_xor(s, 32);
      s4[n] = s;
    }
    float val = (g & 2) ? ((g & 1) ? s4[3] : s4[2]) : ((g & 1) ? s4[1] : s4[0]);
    ptile[(size_t)t * 64 + 16 * g + r] = f2bf(val);
    // rotate pipeline
    t += nw;
    if (t >= ntiles) break;
    tc = ti1; ti1 = ti2; ti2 = ti3;
    s1 = s2;
    a0 = a0n; a1 = a1n; e0v = e1v;
  }
}

// -------------------------------------------------- node GEMM + LN kernel
// Per-node tile range = [firstTile[u], firstTile[u] + ceil(deg[u]/16)).
__global__ __launch_bounds__(256) void ln_node_kernel(
    const short* __restrict__ ptile, const int* __restrict__ firstTile,
    const float* __restrict__ h_in, const int* __restrict__ deg,
    const float* __restrict__ W2, const float* __restrict__ b2,
    const float* __restrict__ gam, const float* __restrict__ bet,
    float* __restrict__ h_out, short* __restrict__ hbf_out, int V_) {
  const int lane = threadIdx.x & 63;
  const int r = lane & 15, g = lane >> 4;
  short8b w2f[4][2];
#pragma unroll
  for (int n = 0; n < 4; ++n)
#pragma unroll
    for (int s = 0; s < 2; ++s)
#pragma unroll
      for (int i = 0; i < 8; ++i) {
        int k = s * 32 + 8 * g + i;
        w2f[n][s][i] = f2bf(W2[k * 64 + n * 16 + r]);
      }
  float b2v[4], gv[4], bv[4];
#pragma unroll
  for (int n = 0; n < 4; ++n) {
    b2v[n] = b2[n * 16 + r]; gv[n] = gam[n * 16 + r]; bv[n] = bet[n * 16 + r];
  }
  const int ntile16 = (V_ + 15) >> 4;
  const int nw = (gridDim.x * blockDim.x) >> 6;
  const int w0 = (blockIdx.x * blockDim.x + threadIdx.x) >> 6;
  for (int tile = w0; tile < ntile16; tile += nw) {
    const int v0 = tile << 4;
    const int u = min(v0 + r, V_ - 1);
    const int t0 = firstTile[u];
    const int t1 = t0 + ((deg[u] + 15) >> 4);   // local count — NOT firstTile[u+1]
    float sum0[8], sum1[8];
#pragma unroll
    for (int i = 0; i < 8; ++i) { sum0[i] = 0.f; sum1[i] = 0.f; }
    for (int tt = t0; tt < t1; ++tt) {
      const short* prow = ptile + (size_t)tt * 64;
      short8b q0 = *reinterpret_cast<const short8b*>(prow + 8 * g);
      short8b q1 = *reinterpret_cast<const short8b*>(prow + 32 + 8 * g);
#pragma unroll
      for (int i = 0; i < 8; ++i) { sum0[i] += bf2f(q0[i]); sum1[i] += bf2f(q1[i]); }
    }
    short8b a0, a1;
#pragma unroll
    for (int i = 0; i < 8; ++i) { a0[i] = f2bf(sum0[i]); a1[i] = f2bf(sum1[i]); }
    f32x4 acc[4];
#pragma unroll
    for (int n = 0; n < 4; ++n) {
      acc[n] = f32x4{0.f, 0.f, 0.f, 0.f};
      acc[n] = __builtin_amdgcn_mfma_f32_16x16x32_bf16(a0, w2f[n][0], acc[n], 0, 0, 0);
      acc[n] = __builtin_amdgcn_mfma_f32_16x16x32_bf16(a1, w2f[n][1], acc[n], 0, 0, 0);
    }
    float x[4][4];  // [i][n]
    float pm[4], pq[4];
#pragma unroll
    for (int i = 0; i < 4; ++i) {
      int u2 = min(v0 + 4 * g + i, V_ - 1);
      int di = deg[u2];
      float inv = di > 0 ? 1.0f / (float)di : 0.0f;
      float hasb = di > 0 ? 1.0f : 0.0f;
      float s = 0.f, q = 0.f;
#pragma unroll
      for (int n = 0; n < 4; ++n) {
        float hv = h_in[(size_t)u2 * 64 + n * 16 + r];
        float xx = hv + acc[n][i] * inv + hasb * b2v[n];
        x[i][n] = xx;
        s += xx; q += xx * xx;
      }
      pm[i] = s; pq[i] = q;
    }
#pragma unroll
    for (int o = 1; o < 16; o <<= 1) {
#pragma unroll
      for (int i = 0; i < 4; ++i) {
        pm[i] += __shfl_xor(pm[i], o);
        pq[i] += __shfl_xor(pq[i], o);
      }
    }
#pragma unroll
    for (int i = 0; i < 4; ++i) {
      int u2 = v0 + 4 * g + i;
      if (u2 < V_) {
        float mean = pm[i] * (1.0f / 64.0f);
        float var = pq[i] * (1.0f / 64.0f) - mean * mean;
        float rs = rsqrtf(var + 1e-5f);
#pragma unroll
        for (int n = 0; n < 4; ++n) {
          float y = (x[i][n] - mean) * rs * gv[n] + bv[n];
          h_out[(size_t)u2 * 64 + n * 16 + r] = y;
          if (hbf_out) hbf_out[(size_t)u2 * 64 + n * 16 + r] = f2bf(y);
        }
      }
    }
  }
}

// ------------------------------------------------------------- props kernel
__global__ void props_kernel(const float* __restrict__ vf,
                             const float* __restrict__ pW1, const float* __restrict__ pb1,
                             const float* __restrict__ pW2, const float* __restrict__ pb2,
                             float* __restrict__ props) {
  __shared__ float tbuf[64];
  const int c = threadIdx.x;  // 0..63
  float w1c[8], w2c[64];
#pragma unroll
  for (int i = 0; i < 8; ++i) w1c[i] = pW1[i * 64 + c];
#pragma unroll
  for (int k = 0; k < 64; ++k) w2c[k] = pW2[k * 64 + c];
  const float b1c = pb1[c], b2c = pb2[c];
  for (int v = 0; v < 64; ++v) {
    float acc = b1c;
#pragma unroll
    for (int i = 0; i < 8; ++i) acc = fmaf(vf[v * 8 + i], w1c[i], acc);
    tbuf[c] = fmaxf(acc, 0.0f);
    __syncthreads();
    float s = b2c;
#pragma unroll
    for (int k = 0; k < 64; ++k) s = fmaf(tbuf[k], w2c[k], s);
    props[v * 64 + c] = s;
    __syncthreads();
  }
}

// -------------------------------------------------------------- final kernel
__global__ void final_kernel(const float* __restrict__ h, const int* __restrict__ cur,
                             const float* __restrict__ props,
                             const float* __restrict__ rg, const float* __restrict__ rb,
                             float* __restrict__ out) {
  const int v = blockIdx.x;
  const int c = threadIdx.x;  // 64 threads
  const int node = cur[v];
  float x = h[(size_t)node * 64 + c] + props[v * 64 + c];
  float m = x;
#pragma unroll
  for (int off = 32; off; off >>= 1) m += __shfl_xor(m, off);
  m *= (1.0f / 64.0f);
  float d = x - m;
  float var = d * d;
#pragma unroll
  for (int off = 32; off; off >>= 1) var += __shfl_xor(var, off);
  var *= (1.0f / 64.0f);
  out[v * 64 + c] = d * rsqrtf(var + 1e-5f) * rg[c] + rb[c];
}

extern "C" void kernel_launch(void* const* d_in, const int* in_sizes, int n_in,
                              void* d_out, int out_size, void* d_ws, size_t ws_size,
                              hipStream_t stream) {
  const float* Z   = (const float*)d_in[0];
  const float* vm  = (const float*)d_in[1];
  const float* vf  = (const float*)d_in[2];
  const float* ea  = (const float*)d_in[3];
  const int*   ei  = (const int*)d_in[4];
  const int*   cur = (const int*)d_in[5];
  const float* nW  = (const float*)d_in[6];
  const float* nb  = (const float*)d_in[7];
  const float* pW1 = (const float*)d_in[8];
  const float* pb1 = (const float*)d_in[9];
  const float* pW2 = (const float*)d_in[10];
  const float* pb2 = (const float*)d_in[11];
  const float* rg  = (const float*)d_in[12];
  const float* rb  = (const float*)d_in[13];
  const float* W1[2] = {(const float*)d_in[14], (const float*)d_in[20]};
  const float* B1[2] = {(const float*)d_in[15], (const float*)d_in[21]};
  const float* W2[2] = {(const float*)d_in[16], (const float*)d_in[22]};
  const float* B2[2] = {(const float*)d_in[17], (const float*)d_in[23]};
  const float* G[2]  = {(const float*)d_in[18], (const float*)d_in[24]};
  const float* BE[2] = {(const float*)d_in[19], (const float*)d_in[25]};

  const int V_ = in_sizes[0] / 64;
  const int E_ = in_sizes[4] / 2;
  const int NTMAX = (E_ >> 4) + V_;  // >= sum(ceil(deg/16))
  const int NB = (V_ + 255) / 256;   // scan blocks (<=256 required)
  const int Vw = (V_ + 7) / 8;       // XCD window size in nodes
  float* out = (float*)d_out;

  char* p = (char*)d_ws;
  auto take = [&](size_t bytes) { char* q = p; p += (bytes + 255) & ~(size_t)255; return q; };
  float* hA      = (float*)take((size_t)V_ * 64 * 4);
  float* hB      = (float*)take((size_t)V_ * 64 * 4);
  short* hAbf    = (short*)take((size_t)V_ * 64 * 2);
  short* hBbf    = (short*)take((size_t)V_ * 64 * 2);
  int*   srcs    = (int*)take((size_t)(E_ + 16) * 4);
  short* eas     = (short*)take((size_t)(E_ + 16) * 16 * 2);
  short* ptile   = (short*)take((size_t)NTMAX * 64 * 2);
  int2*  tinfo   = (int2*)take((size_t)NTMAX * 8);
  int*   deg     = (int*)take((size_t)V_ * 4);
  int*   off     = (int*)take((size_t)V_ * 4);
  int*   cursor  = (int*)take((size_t)V_ * 4);
  int*   firstT  = (int*)take((size_t)(V_ + 1) * 4);
  int*   partD   = (int*)take((size_t)NB * 4);
  int*   partT   = (int*)take((size_t)NB * 4);
  int*   gtot    = (int*)take(256);
  float* props   = (float*)take(64 * 64 * 4);

  // ---- CSR + sorted payload build (once; shared by both layers)
  hipMemsetAsync(deg, 0, (size_t)V_ * 4, stream);
  hipMemsetAsync(srcs + E_, 0, 16 * 4, stream);   // pad: valid node index 0
  deg_kernel<<<(E_ + 255) / 256, 256, 0, stream>>>(ei, deg, E_);
  scanA_kernel<<<NB, 256, 0, stream>>>(deg, partD, partT, V_);
  scanB_kernel<<<1, 256, 0, stream>>>(partD, partT, gtot, NB);
  scanC_kernel<<<NB, 256, 0, stream>>>(deg, partD, partT, off, cursor, firstT, V_);
  tile_fill_kernel<<<(V_ + 255) / 256, 256, 0, stream>>>(deg, off, firstT, tinfo, V_);
  eas_win_kernel<<<2048, 256, 0, stream>>>(ei, ea, cursor, srcs, eas, E_, Vw);

  // ---- embed + props
  embed_mfma<<<784, 256, 0, stream>>>(Z, vm, nW, nb, hA, hAbf, V_);
  props_kernel<<<1, 64, 0, stream>>>(vf, pW1, pb1, pW2, pb2, props);

  // ---- layer 0
  edge_tile_kernel<<<2048, 256, 0, stream>>>(hAbf, srcs, eas, tinfo, gtot,
                                             W1[0], B1[0], ptile, E_);
  ln_node_kernel<<<784, 256, 0, stream>>>(ptile, firstT, hA, deg, W2[0], B2[0],
                                          G[0], BE[0], hB, hBbf, V_);

  // ---- layer 1
  edge_tile_kernel<<<2048, 256, 0, stream>>>(hBbf, srcs, eas, tinfo, gtot,
                                             W1[1], B1[1], ptile, E_);
  ln_node_kernel<<<784, 256, 0, stream>>>(ptile, firstT, hB, deg, W2[1], B2[1],
                                          G[1], BE[1], hA, (short*)nullptr, V_);

  final_kernel<<<64, 64, 0, stream>>>(hA, cur, props, rg, rb, out);
}

// Round 9
// 410.390 us; speedup vs baseline: 1.0156x; 1.0156x over previous
//
#include <hip/hip_runtime.h>
#include <hip/hip_bf16.h>

// V=50000, E=1600000, D=64, EF=16, node_in=74, NV=64 (derived at launch).
// Flat-tile design, R9:
//   CSR (dst-grouped, monotone off via 3-kernel scan) built once.
//   pairs_win: XCD-windowed scatter of {src,eid} (8B/edge; 1.6MB window fits
//     per-XCD L2 -> no write amplification).
//   eas_gather: sequential pass writes srcs[pos] + bf16 eas[pos], gathering
//     ea[eid] (one aligned 64B line per edge, read exactly once).
//   edge_tile: ptile[t] = colsum over tile rows of relu([h[src],ea,1]@W1')
//     (W1' row 80 = b1 flag-bias; masked rows contribute 0). 3-deep pipeline;
//     srcs/eas are sequential streams; only h[src] gather is random.
//   ln_node:  S[u] = sum of ptile rows [firstTile[u], firstTile[u]+ceil(deg/16));
//             h' = LN(h + (S@W2)/deg + b2 [deg>0]).

typedef __attribute__((ext_vector_type(8))) short short8b;   // 8 bf16
typedef __attribute__((ext_vector_type(4))) float f32x4;     // MFMA C/D
typedef __attribute__((ext_vector_type(4))) unsigned int u32x4;

static __device__ __forceinline__ short f2bf(float f) {
  union { __hip_bfloat16 h; short s; } u; u.h = __float2bfloat16(f); return u.s;
}
static __device__ __forceinline__ float bf2f(short s) {
  union { unsigned u; float f; } v; v.u = ((unsigned)(unsigned short)s) << 16; return v.f;
}
static __device__ __forceinline__ short8b zero8() {
  short8b z;
#pragma unroll
  for (int i = 0; i < 8; ++i) z[i] = 0;
  return z;
}
static __device__ __forceinline__ short8b and8(short8b a, unsigned m) {
  u32x4 x = __builtin_bit_cast(u32x4, a);
#pragma unroll
  for (int i = 0; i < 4; ++i) x[i] &= m;
  return __builtin_bit_cast(short8b, x);
}

// ----------------------------------------------------------------- degree
__global__ void deg_kernel(const int* __restrict__ ei, int* __restrict__ deg, int E_) {
  int i = blockIdx.x * blockDim.x + threadIdx.x;
  if (i < E_) atomicAdd(&deg[ei[E_ + i]], 1);
}

// ------------------------------------- monotone exclusive scan (3 kernels)
__global__ void scanA_kernel(const int* __restrict__ deg, int* __restrict__ partD,
                             int* __restrict__ partT, int V_) {
  __shared__ int sd[256], st[256];
  int t = threadIdx.x;
  int v = blockIdx.x * 256 + t;
  int d = (v < V_) ? deg[v] : 0;
  sd[t] = d; st[t] = (d + 15) >> 4;
  __syncthreads();
  for (int o = 128; o; o >>= 1) {
    if (t < o) { sd[t] += sd[t + o]; st[t] += st[t + o]; }
    __syncthreads();
  }
  if (t == 0) { partD[blockIdx.x] = sd[0]; partT[blockIdx.x] = st[0]; }
}

__global__ void scanB_kernel(int* __restrict__ partD, int* __restrict__ partT,
                             int* __restrict__ gtot, int nb) {
  __shared__ int sd[256], st[256];
  int t = threadIdx.x;  // 256 >= nb
  int d = (t < nb) ? partD[t] : 0;
  int tt = (t < nb) ? partT[t] : 0;
  sd[t] = d; st[t] = tt;
  __syncthreads();
  for (int o = 1; o < 256; o <<= 1) {
    int ad = (t >= o) ? sd[t - o] : 0;
    int at = (t >= o) ? st[t - o] : 0;
    __syncthreads();
    sd[t] += ad; st[t] += at;
    __syncthreads();
  }
  if (t < nb) { partD[t] = t ? sd[t - 1] : 0; partT[t] = t ? st[t - 1] : 0; }
  if (t == nb - 1) { gtot[0] = sd[t]; gtot[1] = st[t]; }
}

__global__ void scanC_kernel(const int* __restrict__ deg, const int* __restrict__ partD,
                             const int* __restrict__ partT, int* __restrict__ off,
                             int* __restrict__ cursor, int* __restrict__ firstT, int V_) {
  __shared__ int sd[256], st[256];
  int t = threadIdx.x;
  int v = blockIdx.x * 256 + t;
  int d = (v < V_) ? deg[v] : 0;
  int td = (d + 15) >> 4;
  sd[t] = d; st[t] = td;
  __syncthreads();
  for (int o = 1; o < 256; o <<= 1) {
    int ad = (t >= o) ? sd[t - o] : 0;
    int at = (t >= o) ? st[t - o] : 0;
    __syncthreads();
    sd[t] += ad; st[t] += at;
    __syncthreads();
  }
  if (v < V_) {
    int eoff = partD[blockIdx.x] + sd[t] - d;
    int toff = partT[blockIdx.x] + st[t] - td;
    off[v] = eoff; cursor[v] = eoff; firstT[v] = toff;
  }
}

__global__ void tile_fill_kernel(const int* __restrict__ deg, const int* __restrict__ off,
                                 const int* __restrict__ firstTile, int2* __restrict__ tinfo,
                                 int V_) {
  int v = blockIdx.x * blockDim.x + threadIdx.x;
  if (v >= V_) return;
  int d = deg[v], o = off[v], T0 = firstTile[v];
  int nt = (d + 15) >> 4;
  for (int j = 0; j < nt; ++j)
    tinfo[T0 + j] = make_int2(o + 16 * j, min(16, d - 16 * j));
}

// ---------------- {src,eid} scatter, XCD-windowed (1.6MB window, L2-fits)
__global__ void pairs_win_kernel(const int* __restrict__ ei, int* __restrict__ cursor,
                                 int2* __restrict__ pairs, int E_, int Vw) {
  const int wb  = blockIdx.x & 7;          // XCD id (round-robin mapping)
  const int sub = blockIdx.x >> 3;
  const int nsub = gridDim.x >> 3;
  const int lo = wb * Vw, hi = lo + Vw;
  for (int i = sub * blockDim.x + threadIdx.x; i < E_; i += nsub * blockDim.x) {
    int dst = ei[E_ + i];
    if (dst >= lo && dst < hi) {
      int pos = atomicAdd(&cursor[dst], 1);
      pairs[pos] = make_int2(ei[i], i);
    }
  }
}

// --------------- sequential payload materialization (srcs + sorted eas)
__global__ void eas_gather_kernel(const int2* __restrict__ pairs, const float* __restrict__ ea,
                                  int* __restrict__ srcs, short* __restrict__ eas, int E_) {
  int i = blockIdx.x * blockDim.x + threadIdx.x;
  if (i >= E_) return;
  int2 pr = pairs[i];
  srcs[i] = pr.x;
  const float4* row = reinterpret_cast<const float4*>(ea + (size_t)pr.y * 16);
  float4 q0 = row[0], q1 = row[1], q2 = row[2], q3 = row[3];
  short8b s0, s1;
  s0[0]=f2bf(q0.x); s0[1]=f2bf(q0.y); s0[2]=f2bf(q0.z); s0[3]=f2bf(q0.w);
  s0[4]=f2bf(q1.x); s0[5]=f2bf(q1.y); s0[6]=f2bf(q1.z); s0[7]=f2bf(q1.w);
  s1[0]=f2bf(q2.x); s1[1]=f2bf(q2.y); s1[2]=f2bf(q2.z); s1[3]=f2bf(q2.w);
  s1[4]=f2bf(q3.x); s1[5]=f2bf(q3.y); s1[6]=f2bf(q3.z); s1[7]=f2bf(q3.w);
  short8b* outp = reinterpret_cast<short8b*>(eas + (size_t)i * 16);
  outp[0] = s0; outp[1] = s1;
}

// ------------------------------------------------------- embed (MFMA tiles)
__global__ __launch_bounds__(256) void embed_mfma(
    const float* __restrict__ Z, const float* __restrict__ vm,
    const float* __restrict__ nW, const float* __restrict__ nb,
    float* __restrict__ h, short* __restrict__ hbf, int V_) {
  const int lane = threadIdx.x & 63;
  const int r = lane & 15, g = lane >> 4;
  short8b wf[4][3];
#pragma unroll
  for (int n = 0; n < 4; ++n)
#pragma unroll
    for (int s = 0; s < 3; ++s)
#pragma unroll
      for (int i = 0; i < 8; ++i) {
        int k = s * 32 + 8 * g + i;
        wf[n][s][i] = f2bf(k < 74 ? nW[k * 64 + n * 16 + r] : 0.0f);
      }
  float nb4[4];
#pragma unroll
  for (int n = 0; n < 4; ++n) nb4[n] = nb[n * 16 + r];

  const int ntiles = (V_ + 15) >> 4;
  const int nw = (gridDim.x * blockDim.x) >> 6;
  const int w0 = (blockIdx.x * blockDim.x + threadIdx.x) >> 6;
  for (int tile = w0; tile < ntiles; tile += nw) {
    const int v0 = tile << 4;
    const int vr = min(v0 + r, V_ - 1);
    const float4* z4 = reinterpret_cast<const float4*>(Z + (size_t)vr * 64);
    float4 p0 = z4[2 * g], p1 = z4[2 * g + 1];
    float4 p2 = z4[8 + 2 * g], p3 = z4[9 + 2 * g];
    short8b a0, a1, a2 = zero8();
    a0[0]=f2bf(p0.x); a0[1]=f2bf(p0.y); a0[2]=f2bf(p0.z); a0[3]=f2bf(p0.w);
    a0[4]=f2bf(p1.x); a0[5]=f2bf(p1.y); a0[6]=f2bf(p1.z); a0[7]=f2bf(p1.w);
    a1[0]=f2bf(p2.x); a1[1]=f2bf(p2.y); a1[2]=f2bf(p2.z); a1[3]=f2bf(p2.w);
    a1[4]=f2bf(p3.x); a1[5]=f2bf(p3.y); a1[6]=f2bf(p3.z); a1[7]=f2bf(p3.w);
    const float* vrow = vm + (size_t)vr * 10;
    if (g == 0) {
#pragma unroll
      for (int i = 0; i < 8; ++i) a2[i] = f2bf(vrow[i]);
    } else if (g == 1) {
      a2[0] = f2bf(vrow[8]); a2[1] = f2bf(vrow[9]);
    }
    f32x4 acc[4];
#pragma unroll
    for (int n = 0; n < 4; ++n) {
      acc[n] = f32x4{nb4[n], nb4[n], nb4[n], nb4[n]};
      acc[n] = __builtin_amdgcn_mfma_f32_16x16x32_bf16(a0, wf[n][0], acc[n], 0, 0, 0);
      acc[n] = __builtin_amdgcn_mfma_f32_16x16x32_bf16(a1, wf[n][1], acc[n], 0, 0, 0);
      acc[n] = __builtin_amdgcn_mfma_f32_16x16x32_bf16(a2, wf[n][2], acc[n], 0, 0, 0);
    }
#pragma unroll
    for (int i = 0; i < 4; ++i) {
      int u = v0 + 4 * g + i;
      if (u < V_) {
#pragma unroll
        for (int n = 0; n < 4; ++n) {
          h[(size_t)u * 64 + n * 16 + r] = acc[n][i];
          hbf[(size_t)u * 64 + n * 16 + r] = f2bf(acc[n][i]);
        }
      }
    }
  }
}

// ---------------------------------------------------- edge tile kernel v2
// Sequential srcs/eas streams; only h[src] gather is random.
// Pipeline: srcs 2-ahead -> h 1-ahead; eas 1-ahead (independent); tinfo 3-ahead.
__global__ __launch_bounds__(256) void edge_tile_kernel(
    const short* __restrict__ hbf, const int* __restrict__ srcs,
    const short* __restrict__ eas, const int2* __restrict__ tinfo,
    const int* __restrict__ gtot,
    const float* __restrict__ W1, const float* __restrict__ b1,
    short* __restrict__ ptile, int E_) {
  const int lane = threadIdx.x & 63;
  const int r = lane & 15, g = lane >> 4;
  // W1' fragments: rows 0..79 = W1, row 80 = b1, rows 81..95 = 0
  short8b w1f[4][3];
#pragma unroll
  for (int n = 0; n < 4; ++n)
#pragma unroll
    for (int s = 0; s < 3; ++s)
#pragma unroll
      for (int i = 0; i < 8; ++i) {
        int k = s * 32 + 8 * g + i;
        float wv = (k < 80) ? W1[k * 64 + n * 16 + r]
                 : (k == 80 ? b1[n * 16 + r] : 0.0f);
        w1f[n][s][i] = f2bf(wv);
      }
  const int ntiles = gtot[1];
  const int nw = (gridDim.x * blockDim.x) >> 6;
  int t = (blockIdx.x * blockDim.x + threadIdx.x) >> 6;
  if (t >= ntiles) return;
  auto info = [&](int tt) { return tinfo[min(tt, ntiles - 1)]; };

  // prologue: tile t fully loaded, srcs of t+1 in flight
  int2 tc  = tinfo[t];
  int2 ti1 = info(t + nw);
  int2 ti2 = info(t + 2 * nw);
  int s0 = srcs[tc.x + r];                       // arrays padded +16: no clamp
  short8b e0v = zero8();
  if (g < 2) e0v = *reinterpret_cast<const short8b*>(eas + ((size_t)(tc.x + r)) * 16 + 8 * g);
  const short* hrow0 = hbf + (size_t)s0 * 64;
  short8b a0 = *reinterpret_cast<const short8b*>(hrow0 + 8 * g);
  short8b a1 = *reinterpret_cast<const short8b*>(hrow0 + 32 + 8 * g);
  int s1 = srcs[ti1.x + r];

  while (true) {
    // issue loads for tile t+1 (h from s1; eas sequential)
    const short* hrow1 = hbf + (size_t)s1 * 64;
    short8b a0n = *reinterpret_cast<const short8b*>(hrow1 + 8 * g);
    short8b a1n = *reinterpret_cast<const short8b*>(hrow1 + 32 + 8 * g);
    short8b e1v = zero8();
    if (g < 2) e1v = *reinterpret_cast<const short8b*>(eas + ((size_t)(ti1.x + r)) * 16 + 8 * g);
    // srcs for t+2, tinfo for t+3
    int s2 = srcs[ti2.x + r];
    int2 ti3 = info(t + 3 * nw);
    // tail masking (rows >= nrows contribute 0 via flag-bias trick)
    unsigned m = (r < tc.y) ? 0xFFFFFFFFu : 0u;
    short8b b0 = and8(a0, m);
    short8b b1v_ = and8(a1, m);
    short8b b2_ = zero8();
    if (g < 2) b2_ = and8(e0v, m);
    if (g == 2) b2_[0] = (short)(m & 0x3F80u);  // flag feature = 1.0bf16
    // GEMM1: 16x96 @ 96x64
    f32x4 acc[4];
#pragma unroll
    for (int n = 0; n < 4; ++n) {
      acc[n] = f32x4{0.f, 0.f, 0.f, 0.f};
      acc[n] = __builtin_amdgcn_mfma_f32_16x16x32_bf16(b0, w1f[n][0], acc[n], 0, 0, 0);
      acc[n] = __builtin_amdgcn_mfma_f32_16x16x32_bf16(b1v_, w1f[n][1], acc[n], 0, 0, 0);
      acc[n] = __builtin_amdgcn_mfma_f32_16x16x32_bf16(b2_, w1f[n][2], acc[n], 0, 0, 0);
    }
    // relu + sum over 16 rows
    float s4[4];
#pragma unroll
    for (int n = 0; n < 4; ++n) {
      float s = (fmaxf(acc[n][0], 0.f) + fmaxf(acc[n][1], 0.f))
              + (fmaxf(acc[n][2], 0.f) + fmaxf(acc[n][3], 0.f));
      s += __shfl_xor(s, 16);
      s += __shfl_xor(s, 32);
      s4[n] = s;
    }
    float val = (g & 2) ? ((g & 1) ? s4[3] : s4[2]) : ((g & 1) ? s4[1] : s4[0]);
    ptile[(size_t)t * 64 + 16 * g + r] = f2bf(val);
    // rotate pipeline
    t += nw;
    if (t >= ntiles) break;
    tc = ti1; ti1 = ti2; ti2 = ti3;
    s1 = s2;
    a0 = a0n; a1 = a1n; e0v = e1v;
  }
}

// -------------------------------------------------- node GEMM + LN kernel
// Per-node tile range = [firstTile[u], firstTile[u] + ceil(deg[u]/16)).
__global__ __launch_bounds__(256) void ln_node_kernel(
    const short* __restrict__ ptile, const int* __restrict__ firstTile,
    const float* __restrict__ h_in, const int* __restrict__ deg,
    const float* __restrict__ W2, const float* __restrict__ b2,
    const float* __restrict__ gam, const float* __restrict__ bet,
    float* __restrict__ h_out, short* __restrict__ hbf_out, int V_) {
  const int lane = threadIdx.x & 63;
  const int r = lane & 15, g = lane >> 4;
  short8b w2f[4][2];
#pragma unroll
  for (int n = 0; n < 4; ++n)
#pragma unroll
    for (int s = 0; s < 2; ++s)
#pragma unroll
      for (int i = 0; i < 8; ++i) {
        int k = s * 32 + 8 * g + i;
        w2f[n][s][i] = f2bf(W2[k * 64 + n * 16 + r]);
      }
  float b2v[4], gv[4], bv[4];
#pragma unroll
  for (int n = 0; n < 4; ++n) {
    b2v[n] = b2[n * 16 + r]; gv[n] = gam[n * 16 + r]; bv[n] = bet[n * 16 + r];
  }
  const int ntile16 = (V_ + 15) >> 4;
  const int nw = (gridDim.x * blockDim.x) >> 6;
  const int w0 = (blockIdx.x * blockDim.x + threadIdx.x) >> 6;
  for (int tile = w0; tile < ntile16; tile += nw) {
    const int v0 = tile << 4;
    const int u = min(v0 + r, V_ - 1);
    const int t0 = firstTile[u];
    const int t1 = t0 + ((deg[u] + 15) >> 4);   // local count — NOT firstTile[u+1]
    float sum0[8], sum1[8];
#pragma unroll
    for (int i = 0; i < 8; ++i) { sum0[i] = 0.f; sum1[i] = 0.f; }
    for (int tt = t0; tt < t1; ++tt) {
      const short* prow = ptile + (size_t)tt * 64;
      short8b q0 = *reinterpret_cast<const short8b*>(prow + 8 * g);
      short8b q1 = *reinterpret_cast<const short8b*>(prow + 32 + 8 * g);
#pragma unroll
      for (int i = 0; i < 8; ++i) { sum0[i] += bf2f(q0[i]); sum1[i] += bf2f(q1[i]); }
    }
    short8b a0, a1;
#pragma unroll
    for (int i = 0; i < 8; ++i) { a0[i] = f2bf(sum0[i]); a1[i] = f2bf(sum1[i]); }
    f32x4 acc[4];
#pragma unroll
    for (int n = 0; n < 4; ++n) {
      acc[n] = f32x4{0.f, 0.f, 0.f, 0.f};
      acc[n] = __builtin_amdgcn_mfma_f32_16x16x32_bf16(a0, w2f[n][0], acc[n], 0, 0, 0);
      acc[n] = __builtin_amdgcn_mfma_f32_16x16x32_bf16(a1, w2f[n][1], acc[n], 0, 0, 0);
    }
    float x[4][4];  // [i][n]
    float pm[4], pq[4];
#pragma unroll
    for (int i = 0; i < 4; ++i) {
      int u2 = min(v0 + 4 * g + i, V_ - 1);
      int di = deg[u2];
      float inv = di > 0 ? 1.0f / (float)di : 0.0f;
      float hasb = di > 0 ? 1.0f : 0.0f;
      float s = 0.f, q = 0.f;
#pragma unroll
      for (int n = 0; n < 4; ++n) {
        float hv = h_in[(size_t)u2 * 64 + n * 16 + r];
        float xx = hv + acc[n][i] * inv + hasb * b2v[n];
        x[i][n] = xx;
        s += xx; q += xx * xx;
      }
      pm[i] = s; pq[i] = q;
    }
#pragma unroll
    for (int o = 1; o < 16; o <<= 1) {
#pragma unroll
      for (int i = 0; i < 4; ++i) {
        pm[i] += __shfl_xor(pm[i], o);
        pq[i] += __shfl_xor(pq[i], o);
      }
    }
#pragma unroll
    for (int i = 0; i < 4; ++i) {
      int u2 = v0 + 4 * g + i;
      if (u2 < V_) {
        float mean = pm[i] * (1.0f / 64.0f);
        float var = pq[i] * (1.0f / 64.0f) - mean * mean;
        float rs = rsqrtf(var + 1e-5f);
#pragma unroll
        for (int n = 0; n < 4; ++n) {
          float y = (x[i][n] - mean) * rs * gv[n] + bv[n];
          h_out[(size_t)u2 * 64 + n * 16 + r] = y;
          if (hbf_out) hbf_out[(size_t)u2 * 64 + n * 16 + r] = f2bf(y);
        }
      }
    }
  }
}

// ---------------------------------------- props kernel (1 block / vehicle)
__global__ void props_kernel(const float* __restrict__ vf,
                             const float* __restrict__ pW1, const float* __restrict__ pb1,
                             const float* __restrict__ pW2, const float* __restrict__ pb2,
                             float* __restrict__ props) {
  __shared__ float tbuf[64];
  const int v = blockIdx.x;
  const int c = threadIdx.x;  // 0..63
  float acc = pb1[c];
#pragma unroll
  for (int i = 0; i < 8; ++i) acc = fmaf(vf[v * 8 + i], pW1[i * 64 + c], acc);
  tbuf[c] = fmaxf(acc, 0.0f);
  __syncthreads();
  float s = pb2[c];
#pragma unroll
  for (int k = 0; k < 64; ++k) s = fmaf(tbuf[k], pW2[k * 64 + c], s);
  props[v * 64 + c] = s;
}

// -------------------------------------------------------------- final kernel
__global__ void final_kernel(const float* __restrict__ h, const int* __restrict__ cur,
                             const float* __restrict__ props,
                             const float* __restrict__ rg, const float* __restrict__ rb,
                             float* __restrict__ out) {
  const int v = blockIdx.x;
  const int c = threadIdx.x;  // 64 threads
  const int node = cur[v];
  float x = h[(size_t)node * 64 + c] + props[v * 64 + c];
  float m = x;
#pragma unroll
  for (int off = 32; off; off >>= 1) m += __shfl_xor(m, off);
  m *= (1.0f / 64.0f);
  float d = x - m;
  float var = d * d;
#pragma unroll
  for (int off = 32; off; off >>= 1) var += __shfl_xor(var, off);
  var *= (1.0f / 64.0f);
  out[v * 64 + c] = d * rsqrtf(var + 1e-5f) * rg[c] + rb[c];
}

extern "C" void kernel_launch(void* const* d_in, const int* in_sizes, int n_in,
                              void* d_out, int out_size, void* d_ws, size_t ws_size,
                              hipStream_t stream) {
  const float* Z   = (const float*)d_in[0];
  const float* vm  = (const float*)d_in[1];
  const float* vf  = (const float*)d_in[2];
  const float* ea  = (const float*)d_in[3];
  const int*   ei  = (const int*)d_in[4];
  const int*   cur = (const int*)d_in[5];
  const float* nW  = (const float*)d_in[6];
  const float* nb  = (const float*)d_in[7];
  const float* pW1 = (const float*)d_in[8];
  const float* pb1 = (const float*)d_in[9];
  const float* pW2 = (const float*)d_in[10];
  const float* pb2 = (const float*)d_in[11];
  const float* rg  = (const float*)d_in[12];
  const float* rb  = (const float*)d_in[13];
  const float* W1[2] = {(const float*)d_in[14], (const float*)d_in[20]};
  const float* B1[2] = {(const float*)d_in[15], (const float*)d_in[21]};
  const float* W2[2] = {(const float*)d_in[16], (const float*)d_in[22]};
  const float* B2[2] = {(const float*)d_in[17], (const float*)d_in[23]};
  const float* G[2]  = {(const float*)d_in[18], (const float*)d_in[24]};
  const float* BE[2] = {(const float*)d_in[19], (const float*)d_in[25]};

  const int V_ = in_sizes[0] / 64;
  const int E_ = in_sizes[4] / 2;
  const int NTMAX = (E_ >> 4) + V_;  // >= sum(ceil(deg/16))
  const int NB = (V_ + 255) / 256;   // scan blocks (<=256 required)
  const int Vw = (V_ + 7) / 8;       // XCD window size in nodes
  float* out = (float*)d_out;

  char* p = (char*)d_ws;
  auto take = [&](size_t bytes) { char* q = p; p += (bytes + 255) & ~(size_t)255; return q; };
  float* hA      = (float*)take((size_t)V_ * 64 * 4);
  float* hB      = (float*)take((size_t)V_ * 64 * 4);
  short* hAbf    = (short*)take((size_t)V_ * 64 * 2);
  short* hBbf    = (short*)take((size_t)V_ * 64 * 2);
  int2*  pairs   = (int2*)take((size_t)E_ * 8);
  int*   srcs    = (int*)take((size_t)(E_ + 16) * 4);
  short* eas     = (short*)take((size_t)(E_ + 16) * 16 * 2);
  short* ptile   = (short*)take((size_t)NTMAX * 64 * 2);
  int2*  tinfo   = (int2*)take((size_t)NTMAX * 8);
  int*   deg     = (int*)take((size_t)V_ * 4);
  int*   off     = (int*)take((size_t)V_ * 4);
  int*   cursor  = (int*)take((size_t)V_ * 4);
  int*   firstT  = (int*)take((size_t)(V_ + 1) * 4);
  int*   partD   = (int*)take((size_t)NB * 4);
  int*   partT   = (int*)take((size_t)NB * 4);
  int*   gtot    = (int*)take(256);
  float* props   = (float*)take(64 * 64 * 4);

  // ---- CSR + sorted payload build (once; shared by both layers)
  hipMemsetAsync(deg, 0, (size_t)V_ * 4, stream);
  hipMemsetAsync(srcs + E_, 0, 16 * 4, stream);   // pad: valid node index 0
  deg_kernel<<<(E_ + 255) / 256, 256, 0, stream>>>(ei, deg, E_);
  scanA_kernel<<<NB, 256, 0, stream>>>(deg, partD, partT, V_);
  scanB_kernel<<<1, 256, 0, stream>>>(partD, partT, gtot, NB);
  scanC_kernel<<<NB, 256, 0, stream>>>(deg, partD, partT, off, cursor, firstT, V_);
  tile_fill_kernel<<<(V_ + 255) / 256, 256, 0, stream>>>(deg, off, firstT, tinfo, V_);
  pairs_win_kernel<<<2048, 256, 0, stream>>>(ei, cursor, pairs, E_, Vw);
  eas_gather_kernel<<<(E_ + 255) / 256, 256, 0, stream>>>(pairs, ea, srcs, eas, E_);

  // ---- embed + props
  embed_mfma<<<784, 256, 0, stream>>>(Z, vm, nW, nb, hA, hAbf, V_);
  props_kernel<<<64, 64, 0, stream>>>(vf, pW1, pb1, pW2, pb2, props);

  // ---- layer 0
  edge_tile_kernel<<<2048, 256, 0, stream>>>(hAbf, srcs, eas, tinfo, gtot,
                                             W1[0], B1[0], ptile, E_);
  ln_node_kernel<<<784, 256, 0, stream>>>(ptile, firstT, hA, deg, W2[0], B2[0],
                                          G[0], BE[0], hB, hBbf, V_);

  // ---- layer 1
  edge_tile_kernel<<<2048, 256, 0, stream>>>(hBbf, srcs, eas, tinfo, gtot,
                                             W1[1], B1[1], ptile, E_);
  ln_node_kernel<<<784, 256, 0, stream>>>(ptile, firstT, hB, deg, W2[1], B2[1],
                                          G[1], BE[1], hA, (short*)nullptr, V_);

  final_kernel<<<64, 64, 0, stream>>>(hA, cur, props, rg, rb, out);
}

// Round 10
// 390.622 us; speedup vs baseline: 1.0670x; 1.0506x over previous
//
#include <hip/hip_runtime.h>
#include <hip/hip_bf16.h>

// V=50000, E=1600000, D=64, EF=16, node_in=74, NV=64 (derived at launch).
// Flat-tile design, R10:
//   CSR (dst-grouped, monotone off via 3-kernel scan) built once as
//   pairs[pos]={src,eid} (8B/edge, XCD-windowed scatter -> L2-resident).
//   deg_conv also produces eabf (coalesced ea->bf16).
//   edge_tile v3: ptile[t] = colsum over tile rows of relu([h[src],ea,1]@W1')
//     (W1' row 80 = b1 flag-bias). 3-tile-deep pipeline (pairs 3-ahead,
//     gathers 2-ahead); full-tile fast path skips masking VALU.
//   ln_node:  S[u] = sum of ptile rows [firstTile[u], firstTile[u]+ceil(deg/16));
//             h' = LN(h + (S@W2)/deg + b2 [deg>0]).

typedef __attribute__((ext_vector_type(8))) short short8b;   // 8 bf16
typedef __attribute__((ext_vector_type(4))) float f32x4;     // MFMA C/D
typedef __attribute__((ext_vector_type(4))) unsigned int u32x4;

static __device__ __forceinline__ short f2bf(float f) {
  union { __hip_bfloat16 h; short s; } u; u.h = __float2bfloat16(f); return u.s;
}
static __device__ __forceinline__ float bf2f(short s) {
  union { unsigned u; float f; } v; v.u = ((unsigned)(unsigned short)s) << 16; return v.f;
}
static __device__ __forceinline__ short8b zero8() {
  short8b z;
#pragma unroll
  for (int i = 0; i < 8; ++i) z[i] = 0;
  return z;
}
static __device__ __forceinline__ short8b and8(short8b a, unsigned m) {
  u32x4 x = __builtin_bit_cast(u32x4, a);
#pragma unroll
  for (int i = 0; i < 4; ++i) x[i] &= m;
  return __builtin_bit_cast(short8b, x);
}

// ---------------------------------------------- deg + coalesced ea->bf16
__global__ void deg_conv_kernel(const int* __restrict__ ei, const float* __restrict__ ea,
                                int* __restrict__ deg, short* __restrict__ eabf, int E_) {
  int i = blockIdx.x * blockDim.x + threadIdx.x;
  if (i >= E_) return;
  atomicAdd(&deg[ei[E_ + i]], 1);
  const float4* row = reinterpret_cast<const float4*>(ea + (size_t)i * 16);
  float4 q0 = row[0], q1 = row[1], q2 = row[2], q3 = row[3];
  short8b s0, s1;
  s0[0]=f2bf(q0.x); s0[1]=f2bf(q0.y); s0[2]=f2bf(q0.z); s0[3]=f2bf(q0.w);
  s0[4]=f2bf(q1.x); s0[5]=f2bf(q1.y); s0[6]=f2bf(q1.z); s0[7]=f2bf(q1.w);
  s1[0]=f2bf(q2.x); s1[1]=f2bf(q2.y); s1[2]=f2bf(q2.z); s1[3]=f2bf(q2.w);
  s1[4]=f2bf(q3.x); s1[5]=f2bf(q3.y); s1[6]=f2bf(q3.z); s1[7]=f2bf(q3.w);
  short8b* outp = reinterpret_cast<short8b*>(eabf + (size_t)i * 16);
  outp[0] = s0; outp[1] = s1;
}

// ------------------------------------- monotone exclusive scan (3 kernels)
__global__ void scanA_kernel(const int* __restrict__ deg, int* __restrict__ partD,
                             int* __restrict__ partT, int V_) {
  __shared__ int sd[256], st[256];
  int t = threadIdx.x;
  int v = blockIdx.x * 256 + t;
  int d = (v < V_) ? deg[v] : 0;
  sd[t] = d; st[t] = (d + 15) >> 4;
  __syncthreads();
  for (int o = 128; o; o >>= 1) {
    if (t < o) { sd[t] += sd[t + o]; st[t] += st[t + o]; }
    __syncthreads();
  }
  if (t == 0) { partD[blockIdx.x] = sd[0]; partT[blockIdx.x] = st[0]; }
}

__global__ void scanB_kernel(int* __restrict__ partD, int* __restrict__ partT,
                             int* __restrict__ gtot, int nb) {
  __shared__ int sd[256], st[256];
  int t = threadIdx.x;  // 256 >= nb
  int d = (t < nb) ? partD[t] : 0;
  int tt = (t < nb) ? partT[t] : 0;
  sd[t] = d; st[t] = tt;
  __syncthreads();
  for (int o = 1; o < 256; o <<= 1) {
    int ad = (t >= o) ? sd[t - o] : 0;
    int at = (t >= o) ? st[t - o] : 0;
    __syncthreads();
    sd[t] += ad; st[t] += at;
    __syncthreads();
  }
  if (t < nb) { partD[t] = t ? sd[t - 1] : 0; partT[t] = t ? st[t - 1] : 0; }
  if (t == nb - 1) { gtot[0] = sd[t]; gtot[1] = st[t]; }
}

__global__ void scanC_kernel(const int* __restrict__ deg, const int* __restrict__ partD,
                             const int* __restrict__ partT, int* __restrict__ off,
                             int* __restrict__ cursor, int* __restrict__ firstT, int V_) {
  __shared__ int sd[256], st[256];
  int t = threadIdx.x;
  int v = blockIdx.x * 256 + t;
  int d = (v < V_) ? deg[v] : 0;
  int td = (d + 15) >> 4;
  sd[t] = d; st[t] = td;
  __syncthreads();
  for (int o = 1; o < 256; o <<= 1) {
    int ad = (t >= o) ? sd[t - o] : 0;
    int at = (t >= o) ? st[t - o] : 0;
    __syncthreads();
    sd[t] += ad; st[t] += at;
    __syncthreads();
  }
  if (v < V_) {
    int eoff = partD[blockIdx.x] + sd[t] - d;
    int toff = partT[blockIdx.x] + st[t] - td;
    off[v] = eoff; cursor[v] = eoff; firstT[v] = toff;
  }
}

__global__ void tile_fill_kernel(const int* __restrict__ deg, const int* __restrict__ off,
                                 const int* __restrict__ firstTile, int2* __restrict__ tinfo,
                                 int V_) {
  int v = blockIdx.x * blockDim.x + threadIdx.x;
  if (v >= V_) return;
  int d = deg[v], o = off[v], T0 = firstTile[v];
  int nt = (d + 15) >> 4;
  for (int j = 0; j < nt; ++j)
    tinfo[T0 + j] = make_int2(o + 16 * j, min(16, d - 16 * j));
}

// ---------------- {src,eid} scatter, XCD-windowed (1.6MB window, L2-fits)
__global__ void pairs_win_kernel(const int* __restrict__ ei, int* __restrict__ cursor,
                                 int2* __restrict__ pairs, int E_, int Vw) {
  const int wb  = blockIdx.x & 7;          // XCD id (round-robin mapping)
  const int sub = blockIdx.x >> 3;
  const int nsub = gridDim.x >> 3;
  const int lo = wb * Vw, hi = lo + Vw;
  for (int i = sub * blockDim.x + threadIdx.x; i < E_; i += nsub * blockDim.x) {
    int dst = ei[E_ + i];
    if (dst >= lo && dst < hi) {
      int pos = atomicAdd(&cursor[dst], 1);
      pairs[pos] = make_int2(ei[i], i);
    }
  }
}

// ------------------------------------------------------- embed (MFMA tiles)
__global__ __launch_bounds__(256) void embed_mfma(
    const float* __restrict__ Z, const float* __restrict__ vm,
    const float* __restrict__ nW, const float* __restrict__ nb,
    float* __restrict__ h, short* __restrict__ hbf, int V_) {
  const int lane = threadIdx.x & 63;
  const int r = lane & 15, g = lane >> 4;
  short8b wf[4][3];
#pragma unroll
  for (int n = 0; n < 4; ++n)
#pragma unroll
    for (int s = 0; s < 3; ++s)
#pragma unroll
      for (int i = 0; i < 8; ++i) {
        int k = s * 32 + 8 * g + i;
        wf[n][s][i] = f2bf(k < 74 ? nW[k * 64 + n * 16 + r] : 0.0f);
      }
  float nb4[4];
#pragma unroll
  for (int n = 0; n < 4; ++n) nb4[n] = nb[n * 16 + r];

  const int ntiles = (V_ + 15) >> 4;
  const int nw = (gridDim.x * blockDim.x) >> 6;
  const int w0 = (blockIdx.x * blockDim.x + threadIdx.x) >> 6;
  for (int tile = w0; tile < ntiles; tile += nw) {
    const int v0 = tile << 4;
    const int vr = min(v0 + r, V_ - 1);
    const float4* z4 = reinterpret_cast<const float4*>(Z + (size_t)vr * 64);
    float4 p0 = z4[2 * g], p1 = z4[2 * g + 1];
    float4 p2 = z4[8 + 2 * g], p3 = z4[9 + 2 * g];
    short8b a0, a1, a2 = zero8();
    a0[0]=f2bf(p0.x); a0[1]=f2bf(p0.y); a0[2]=f2bf(p0.z); a0[3]=f2bf(p0.w);
    a0[4]=f2bf(p1.x); a0[5]=f2bf(p1.y); a0[6]=f2bf(p1.z); a0[7]=f2bf(p1.w);
    a1[0]=f2bf(p2.x); a1[1]=f2bf(p2.y); a1[2]=f2bf(p2.z); a1[3]=f2bf(p2.w);
    a1[4]=f2bf(p3.x); a1[5]=f2bf(p3.y); a1[6]=f2bf(p3.z); a1[7]=f2bf(p3.w);
    const float* vrow = vm + (size_t)vr * 10;
    if (g == 0) {
#pragma unroll
      for (int i = 0; i < 8; ++i) a2[i] = f2bf(vrow[i]);
    } else if (g == 1) {
      a2[0] = f2bf(vrow[8]); a2[1] = f2bf(vrow[9]);
    }
    f32x4 acc[4];
#pragma unroll
    for (int n = 0; n < 4; ++n) {
      acc[n] = f32x4{nb4[n], nb4[n], nb4[n], nb4[n]};
      acc[n] = __builtin_amdgcn_mfma_f32_16x16x32_bf16(a0, wf[n][0], acc[n], 0, 0, 0);
      acc[n] = __builtin_amdgcn_mfma_f32_16x16x32_bf16(a1, wf[n][1], acc[n], 0, 0, 0);
      acc[n] = __builtin_amdgcn_mfma_f32_16x16x32_bf16(a2, wf[n][2], acc[n], 0, 0, 0);
    }
#pragma unroll
    for (int i = 0; i < 4; ++i) {
      int u = v0 + 4 * g + i;
      if (u < V_) {
#pragma unroll
        for (int n = 0; n < 4; ++n) {
          h[(size_t)u * 64 + n * 16 + r] = acc[n][i];
          hbf[(size_t)u * 64 + n * 16 + r] = f2bf(acc[n][i]);
        }
      }
    }
  }
}

// ---------------------------------------------------- edge tile kernel v3
// 3-tile-deep pipeline: pairs 3-ahead, h/ea gathers 2-ahead, tinfo 4-ahead.
// Full-tile fast path (tc.y == 16, wave-uniform) skips masking VALU.
__global__ __launch_bounds__(256) void edge_tile_kernel(
    const short* __restrict__ hbf, const short* __restrict__ eabf,
    const int2* __restrict__ pairs, const int2* __restrict__ tinfo,
    const int* __restrict__ gtot,
    const float* __restrict__ W1, const float* __restrict__ b1,
    short* __restrict__ ptile, int E_) {
  const int lane = threadIdx.x & 63;
  const int r = lane & 15, g = lane >> 4;
  // W1' fragments: rows 0..79 = W1, row 80 = b1, rows 81..95 = 0
  short8b w1f[4][3];
#pragma unroll
  for (int n = 0; n < 4; ++n)
#pragma unroll
    for (int s = 0; s < 3; ++s)
#pragma unroll
      for (int i = 0; i < 8; ++i) {
        int k = s * 32 + 8 * g + i;
        float wv = (k < 80) ? W1[k * 64 + n * 16 + r]
                 : (k == 80 ? b1[n * 16 + r] : 0.0f);
        w1f[n][s][i] = f2bf(wv);
      }
  const int ntiles = gtot[1];
  const int nw = (gridDim.x * blockDim.x) >> 6;
  int t = (blockIdx.x * blockDim.x + threadIdx.x) >> 6;
  if (t >= ntiles) return;
  auto info = [&](int tt) { return tinfo[min(tt, ntiles - 1)]; };
  auto gatherA = [&](int2 pr, short8b& A0, short8b& A1, short8b& EV) {
    const short* hrow = hbf + (size_t)pr.x * 64;
    A0 = *reinterpret_cast<const short8b*>(hrow + 8 * g);
    A1 = *reinterpret_cast<const short8b*>(hrow + 32 + 8 * g);
    EV = zero8();
    if (g < 2) EV = *reinterpret_cast<const short8b*>(eabf + (size_t)pr.y * 16 + 8 * g);
  };

  // prologue (pairs array padded +16 with {0,0}: tc.x + r always in-bounds)
  int2 tc  = tinfo[t];
  int2 ti1 = info(t + nw);
  int2 ti2 = info(t + 2 * nw);
  int2 ti3 = info(t + 3 * nw);
  int2 pc = pairs[tc.x + r];
  int2 p1 = pairs[ti1.x + r];
  int2 p2 = pairs[ti2.x + r];
  short8b a0c, a1c, evc, a0n, a1n, evn;
  gatherA(pc, a0c, a1c, evc);
  gatherA(p1, a0n, a1n, evn);

  while (true) {
    // issue gathers for tile t+2nw (2 tiles ahead of compute)
    short8b a0nn, a1nn, evnn;
    gatherA(p2, a0nn, a1nn, evnn);
    // prefetch pairs for t+3nw, tinfo for t+4nw
    int2 p3 = pairs[ti3.x + r];
    int2 ti4 = info(t + 4 * nw);
    // build A fragments for current tile
    short8b b0, b1v_, b2_;
    if (tc.y == 16) {          // full tile (wave-uniform): no masking
      b0 = a0c; b1v_ = a1c;
      b2_ = zero8();
      if (g < 2) b2_ = evc;
      if (g == 2) b2_[0] = (short)0x3F80;       // flag = 1.0bf16
    } else {
      unsigned m = (r < tc.y) ? 0xFFFFFFFFu : 0u;
      b0 = and8(a0c, m);
      b1v_ = and8(a1c, m);
      b2_ = zero8();
      if (g < 2) b2_ = and8(evc, m);
      if (g == 2) b2_[0] = (short)(m & 0x3F80u);
    }
    // GEMM1: 16x96 @ 96x64
    f32x4 acc[4];
#pragma unroll
    for (int n = 0; n < 4; ++n) {
      acc[n] = f32x4{0.f, 0.f, 0.f, 0.f};
      acc[n] = __builtin_amdgcn_mfma_f32_16x16x32_bf16(b0, w1f[n][0], acc[n], 0, 0, 0);
      acc[n] = __builtin_amdgcn_mfma_f32_16x16x32_bf16(b1v_, w1f[n][1], acc[n], 0, 0, 0);
      acc[n] = __builtin_amdgcn_mfma_f32_16x16x32_bf16(b2_, w1f[n][2], acc[n], 0, 0, 0);
    }
    // relu + sum over 16 rows
    float s4[4];
#pragma unroll
    for (int n = 0; n < 4; ++n) {
      float s = (fmaxf(acc[n][0], 0.f) + fmaxf(acc[n][1], 0.f))
              + (fmaxf(acc[n][2], 0.f) + fmaxf(acc[n][3], 0.f));
      s += __shfl_xor(s, 16);
      s += __shfl_xor(s, 32);
      s4[n] = s;
    }
    float val = (g & 2) ? ((g & 1) ? s4[3] : s4[2]) : ((g & 1) ? s4[1] : s4[0]);
    ptile[(size_t)t * 64 + 16 * g + r] = f2bf(val);
    // rotate pipeline
    t += nw;
    if (t >= ntiles) break;
    tc = ti1; ti1 = ti2; ti2 = ti3; ti3 = ti4;
    pc = p1; p1 = p2; p2 = p3;
    a0c = a0n; a1c = a1n; evc = evn;
    a0n = a0nn; a1n = a1nn; evn = evnn;
  }
}

// -------------------------------------------------- node GEMM + LN kernel
// Per-node tile range = [firstTile[u], firstTile[u] + ceil(deg[u]/16)).
__global__ __launch_bounds__(256) void ln_node_kernel(
    const short* __restrict__ ptile, const int* __restrict__ firstTile,
    const float* __restrict__ h_in, const int* __restrict__ deg,
    const float* __restrict__ W2, const float* __restrict__ b2,
    const float* __restrict__ gam, const float* __restrict__ bet,
    float* __restrict__ h_out, short* __restrict__ hbf_out, int V_) {
  const int lane = threadIdx.x & 63;
  const int r = lane & 15, g = lane >> 4;
  short8b w2f[4][2];
#pragma unroll
  for (int n = 0; n < 4; ++n)
#pragma unroll
    for (int s = 0; s < 2; ++s)
#pragma unroll
      for (int i = 0; i < 8; ++i) {
        int k = s * 32 + 8 * g + i;
        w2f[n][s][i] = f2bf(W2[k * 64 + n * 16 + r]);
      }
  float b2v[4], gv[4], bv[4];
#pragma unroll
  for (int n = 0; n < 4; ++n) {
    b2v[n] = b2[n * 16 + r]; gv[n] = gam[n * 16 + r]; bv[n] = bet[n * 16 + r];
  }
  const int ntile16 = (V_ + 15) >> 4;
  const int nw = (gridDim.x * blockDim.x) >> 6;
  const int w0 = (blockIdx.x * blockDim.x + threadIdx.x) >> 6;
  for (int tile = w0; tile < ntile16; tile += nw) {
    const int v0 = tile << 4;
    const int u = min(v0 + r, V_ - 1);
    const int t0 = firstTile[u];
    const int t1 = t0 + ((deg[u] + 15) >> 4);   // local count — NOT firstTile[u+1]
    float sum0[8], sum1[8];
#pragma unroll
    for (int i = 0; i < 8; ++i) { sum0[i] = 0.f; sum1[i] = 0.f; }
    for (int tt = t0; tt < t1; ++tt) {
      const short* prow = ptile + (size_t)tt * 64;
      short8b q0 = *reinterpret_cast<const short8b*>(prow + 8 * g);
      short8b q1 = *reinterpret_cast<const short8b*>(prow + 32 + 8 * g);
#pragma unroll
      for (int i = 0; i < 8; ++i) { sum0[i] += bf2f(q0[i]); sum1[i] += bf2f(q1[i]); }
    }
    short8b a0, a1;
#pragma unroll
    for (int i = 0; i < 8; ++i) { a0[i] = f2bf(sum0[i]); a1[i] = f2bf(sum1[i]); }
    f32x4 acc[4];
#pragma unroll
    for (int n = 0; n < 4; ++n) {
      acc[n] = f32x4{0.f, 0.f, 0.f, 0.f};
      acc[n] = __builtin_amdgcn_mfma_f32_16x16x32_bf16(a0, w2f[n][0], acc[n], 0, 0, 0);
      acc[n] = __builtin_amdgcn_mfma_f32_16x16x32_bf16(a1, w2f[n][1], acc[n], 0, 0, 0);
    }
    float x[4][4];  // [i][n]
    float pm[4], pq[4];
#pragma unroll
    for (int i = 0; i < 4; ++i) {
      int u2 = min(v0 + 4 * g + i, V_ - 1);
      int di = deg[u2];
      float inv = di > 0 ? 1.0f / (float)di : 0.0f;
      float hasb = di > 0 ? 1.0f : 0.0f;
      float s = 0.f, q = 0.f;
#pragma unroll
      for (int n = 0; n < 4; ++n) {
        float hv = h_in[(size_t)u2 * 64 + n * 16 + r];
        float xx = hv + acc[n][i] * inv + hasb * b2v[n];
        x[i][n] = xx;
        s += xx; q += xx * xx;
      }
      pm[i] = s; pq[i] = q;
    }
#pragma unroll
    for (int o = 1; o < 16; o <<= 1) {
#pragma unroll
      for (int i = 0; i < 4; ++i) {
        pm[i] += __shfl_xor(pm[i], o);
        pq[i] += __shfl_xor(pq[i], o);
      }
    }
#pragma unroll
    for (int i = 0; i < 4; ++i) {
      int u2 = v0 + 4 * g + i;
      if (u2 < V_) {
        float mean = pm[i] * (1.0f / 64.0f);
        float var = pq[i] * (1.0f / 64.0f) - mean * mean;
        float rs = rsqrtf(var + 1e-5f);
#pragma unroll
        for (int n = 0; n < 4; ++n) {
          float y = (x[i][n] - mean) * rs * gv[n] + bv[n];
          h_out[(size_t)u2 * 64 + n * 16 + r] = y;
          if (hbf_out) hbf_out[(size_t)u2 * 64 + n * 16 + r] = f2bf(y);
        }
      }
    }
  }
}

// ---------------------------------------- props kernel (1 block / vehicle)
__global__ void props_kernel(const float* __restrict__ vf,
                             const float* __restrict__ pW1, const float* __restrict__ pb1,
                             const float* __restrict__ pW2, const float* __restrict__ pb2,
                             float* __restrict__ props) {
  __shared__ float tbuf[64];
  const int v = blockIdx.x;
  const int c = threadIdx.x;  // 0..63
  float acc = pb1[c];
#pragma unroll
  for (int i = 0; i < 8; ++i) acc = fmaf(vf[v * 8 + i], pW1[i * 64 + c], acc);
  tbuf[c] = fmaxf(acc, 0.0f);
  __syncthreads();
  float s = pb2[c];
#pragma unroll
  for (int k = 0; k < 64; ++k) s = fmaf(tbuf[k], pW2[k * 64 + c], s);
  props[v * 64 + c] = s;
}

// -------------------------------------------------------------- final kernel
__global__ void final_kernel(const float* __restrict__ h, const int* __restrict__ cur,
                             const float* __restrict__ props,
                             const float* __restrict__ rg, const float* __restrict__ rb,
                             float* __restrict__ out) {
  const int v = blockIdx.x;
  const int c = threadIdx.x;  // 64 threads
  const int node = cur[v];
  float x = h[(size_t)node * 64 + c] + props[v * 64 + c];
  float m = x;
#pragma unroll
  for (int off = 32; off; off >>= 1) m += __shfl_xor(m, off);
  m *= (1.0f / 64.0f);
  float d = x - m;
  float var = d * d;
#pragma unroll
  for (int off = 32; off; off >>= 1) var += __shfl_xor(var, off);
  var *= (1.0f / 64.0f);
  out[v * 64 + c] = d * rsqrtf(var + 1e-5f) * rg[c] + rb[c];
}

extern "C" void kernel_launch(void* const* d_in, const int* in_sizes, int n_in,
                              void* d_out, int out_size, void* d_ws, size_t ws_size,
                              hipStream_t stream) {
  const float* Z   = (const float*)d_in[0];
  const float* vm  = (const float*)d_in[1];
  const float* vf  = (const float*)d_in[2];
  const float* ea  = (const float*)d_in[3];
  const int*   ei  = (const int*)d_in[4];
  const int*   cur = (const int*)d_in[5];
  const float* nW  = (const float*)d_in[6];
  const float* nb  = (const float*)d_in[7];
  const float* pW1 = (const float*)d_in[8];
  const float* pb1 = (const float*)d_in[9];
  const float* pW2 = (const float*)d_in[10];
  const float* pb2 = (const float*)d_in[11];
  const float* rg  = (const float*)d_in[12];
  const float* rb  = (const float*)d_in[13];
  const float* W1[2] = {(const float*)d_in[14], (const float*)d_in[20]};
  const float* B1[2] = {(const float*)d_in[15], (const float*)d_in[21]};
  const float* W2[2] = {(const float*)d_in[16], (const float*)d_in[22]};
  const float* B2[2] = {(const float*)d_in[17], (const float*)d_in[23]};
  const float* G[2]  = {(const float*)d_in[18], (const float*)d_in[24]};
  const float* BE[2] = {(const float*)d_in[19], (const float*)d_in[25]};

  const int V_ = in_sizes[0] / 64;
  const int E_ = in_sizes[4] / 2;
  const int NTMAX = (E_ >> 4) + V_;  // >= sum(ceil(deg/16))
  const int NB = (V_ + 255) / 256;   // scan blocks (<=256 required)
  const int Vw = (V_ + 7) / 8;       // XCD window size in nodes
  float* out = (float*)d_out;

  char* p = (char*)d_ws;
  auto take = [&](size_t bytes) { char* q = p; p += (bytes + 255) & ~(size_t)255; return q; };
  float* hA      = (float*)take((size_t)V_ * 64 * 4);
  float* hB      = (float*)take((size_t)V_ * 64 * 4);
  short* hAbf    = (short*)take((size_t)V_ * 64 * 2);
  short* hBbf    = (short*)take((size_t)V_ * 64 * 2);
  short* eabf    = (short*)take((size_t)E_ * 16 * 2);
  int2*  pairs   = (int2*)take((size_t)(E_ + 16) * 8);
  short* ptile   = (short*)take((size_t)NTMAX * 64 * 2);
  int2*  tinfo   = (int2*)take((size_t)NTMAX * 8);
  int*   deg     = (int*)take((size_t)V_ * 4);
  int*   off     = (int*)take((size_t)V_ * 4);
  int*   cursor  = (int*)take((size_t)V_ * 4);
  int*   firstT  = (int*)take((size_t)(V_ + 1) * 4);
  int*   partD   = (int*)take((size_t)NB * 4);
  int*   partT   = (int*)take((size_t)NB * 4);
  int*   gtot    = (int*)take(256);
  float* props   = (float*)take(64 * 64 * 4);

  // ---- CSR + pairs build (once; shared by both layers)
  hipMemsetAsync(deg, 0, (size_t)V_ * 4, stream);
  hipMemsetAsync(pairs + E_, 0, 16 * 8, stream);   // pad: valid {src=0,eid=0}
  deg_conv_kernel<<<(E_ + 255) / 256, 256, 0, stream>>>(ei, ea, deg, eabf, E_);
  scanA_kernel<<<NB, 256, 0, stream>>>(deg, partD, partT, V_);
  scanB_kernel<<<1, 256, 0, stream>>>(partD, partT, gtot, NB);
  scanC_kernel<<<NB, 256, 0, stream>>>(deg, partD, partT, off, cursor, firstT, V_);
  tile_fill_kernel<<<(V_ + 255) / 256, 256, 0, stream>>>(deg, off, firstT, tinfo, V_);
  pairs_win_kernel<<<2048, 256, 0, stream>>>(ei, cursor, pairs, E_, Vw);

  // ---- embed + props
  embed_mfma<<<784, 256, 0, stream>>>(Z, vm, nW, nb, hA, hAbf, V_);
  props_kernel<<<64, 64, 0, stream>>>(vf, pW1, pb1, pW2, pb2, props);

  // ---- layer 0
  edge_tile_kernel<<<2048, 256, 0, stream>>>(hAbf, eabf, pairs, tinfo, gtot,
                                             W1[0], B1[0], ptile, E_);
  ln_node_kernel<<<784, 256, 0, stream>>>(ptile, firstT, hA, deg, W2[0], B2[0],
                                          G[0], BE[0], hB, hBbf, V_);

  // ---- layer 1
  edge_tile_kernel<<<2048, 256, 0, stream>>>(hBbf, eabf, pairs, tinfo, gtot,
                                             W1[1], B1[1], ptile, E_);
  ln_node_kernel<<<784, 256, 0, stream>>>(ptile, firstT, hB, deg, W2[1], B2[1],
                                          G[1], BE[1], hA, (short*)nullptr, V_);

  final_kernel<<<64, 64, 0, stream>>>(hA, cur, props, rg, rb, out);
}